// Round 1
// baseline (4747.966 us; speedup 1.0000x reference)
//
#include <hip/hip_runtime.h>
#include <stdint.h>

// Problem constants
#define BB   32      // batch
#define SS   512     // seq len
#define EE   256     // input dim
#define HH   256     // hidden
#define H4   1024    // 4*H
#define HC   16      // h-columns owned per workgroup
#define NG   16      // slices (WGs) per direction
#define NWG  32      // total WGs (2 directions)
#define NTHR 512     // threads per WG (8 waves)

typedef short bf16x8 __attribute__((ext_vector_type(8)));
typedef float f32x4  __attribute__((ext_vector_type(4)));

// LDS layout (bytes)
#define HF_OFF  0        // h fragments (blended h_t; temporarily h_new pre-blend) 16KB
#define SF_OFF  16384    // s fragments 16KB
#define XB_OFF  32768    // x_t fragments 16KB
#define ZB_OFF  49152    // z tiles f32 [2mt][4gate][16][16] 8KB
#define US_OFF  57344    // s@Us partial f32 [2][16][16] 2KB
#define UH_OFF  59392    // h_new@Uh partial f32 [2][16][16] 2KB
#define CB_OFF  61440    // c state f32 [32][16] 2KB
#define MB_OFF  63488    // mask, double buffered [2][32] f32 256B
#define SMEM_BYTES 63744

__device__ __forceinline__ float bf2f(uint32_t u) {
  union { uint32_t i; float f; } v; v.i = u << 16; return v.f;
}
__device__ __forceinline__ uint32_t f2bf(float f) {
  union { float f; uint32_t i; } v; v.f = f;
  return (v.i + 0x7fffu + ((v.i >> 16) & 1u)) >> 16;
}
__device__ __forceinline__ float sigm(float x) { return 1.f / (1.f + __expf(-x)); }
__device__ __forceinline__ float tanhfast(float x) {
  float e = __expf(2.f * x);
  return 1.f - 2.f / (1.f + e);
}
// byte offset of element (batch m, k) inside a 16KB fragment region.
// Fragment blocks: [(m>>4)*8 + (k>>5)] of 1KB; within block lane=(m&15)+16*((k>>3)&3), byte=(k&7)*2
__device__ __forceinline__ int fragAddr(int m, int k) {
  return (((m >> 4) * 8 + (k >> 5)) << 10) + (((m & 15) + (((k >> 3) & 3) << 4)) << 4) + ((k & 7) << 1);
}
__device__ __forceinline__ f32x4 mfma16(bf16x8 a, bf16x8 b, f32x4 c) {
  return __builtin_amdgcn_mfma_f32_16x16x32_bf16(a, b, c, 0, 0, 0);
}

__global__ void init_flags(uint32_t* f) {
  int i = blockIdx.x * blockDim.x + threadIdx.x;
  if (i < 1024) f[i] = 0u;
}

__global__ void __launch_bounds__(NTHR)
slstm_persistent(const float* __restrict__ x, const float* __restrict__ mask,
                 const float* Wx_f, const float* Wh_f, const float* Ws_f, const float* b_f,
                 const float* Us_f, const float* Uh_f, const float* bs_f,
                 const float* Wx_r, const float* Wh_r, const float* Ws_r, const float* b_r,
                 const float* Us_r, const float* Uh_r, const float* bs_r,
                 float* __restrict__ out, uint32_t* __restrict__ wsbase) {
  __shared__ __align__(16) char smem[SMEM_BYTES];

  const int bid = blockIdx.x;
  const int dir = bid >> 4;      // 0 fwd, 1 rev
  const int g   = bid & 15;      // slice id
  const int tid = threadIdx.x;
  const int w    = tid >> 6;     // wave 0..7
  const int lane = tid & 63;
  const int lr = lane & 15, lq = lane >> 4;
  const int mt = w & 1;          // m-tile (batches 16mt..16mt+15)
  const int q  = w >> 1;         // gate 0..3 (i,f,g,o)

  const float* Wx = dir ? Wx_r : Wx_f;
  const float* Wh = dir ? Wh_r : Wh_f;
  const float* Ws = dir ? Ws_r : Ws_f;
  const float* bv = dir ? b_r  : b_f;
  const float* Us = dir ? Us_r : Us_f;
  const float* Uh = dir ? Uh_r : Uh_f;
  const float* bs = dir ? bs_r : bs_f;

  uint32_t* flags = wsbase;                    // [2dir][2kind][16sl][16pad]
  uint32_t* hbufB = wsbase + 1024;             // [2dir][2par][16sl][256] words
  uint32_t* sbufB = wsbase + 1024 + 16384;
  uint32_t* flagH = flags + (dir * 2 + 0) * NG * 16;
  uint32_t* flagS = flags + (dir * 2 + 1) * NG * 16;

  // ---- preload weight B-fragments into registers (persistent) ----
  bf16x8 WxF[8], WhF[8], WsF[8], UF[8];
  {
    const int col = q * HH + g * HC + lr;   // z-column for this wave/lane
    #pragma unroll
    for (int kk = 0; kk < 8; ++kk) {
      bf16x8 vx, vh, vs;
      #pragma unroll
      for (int i = 0; i < 8; ++i) {
        int k = kk * 32 + lq * 8 + i;
        vx[i] = (short)f2bf(Wx[k * H4 + col]);
        vh[i] = (short)f2bf(Wh[k * H4 + col]);
        vs[i] = (short)f2bf(Ws[k * H4 + col]);
      }
      WxF[kk] = vx; WhF[kk] = vh; WsF[kk] = vs;
    }
  }
  if (w < 4) {                      // waves 0,1: Us ; waves 2,3: Uh
    const float* U = (w < 2) ? Us : Uh;
    const int colU = g * HC + lr;
    #pragma unroll
    for (int kk = 0; kk < 8; ++kk) {
      bf16x8 vu;
      #pragma unroll
      for (int i = 0; i < 8; ++i) {
        int k = kk * 32 + lq * 8 + i;
        vu[i] = (short)f2bf(U[k * HH + colU]);
      }
      UF[kk] = vu;
    }
  }
  const float breg  = bv[q * HH + g * HC + lr];
  const float bsreg = bs[g * HC + (tid & 15)];

  // ---- zero state LDS (h, s, c) ----
  {
    uint4* p = (uint4*)(smem);  // HF+SF = 32KB = 2048 x uint4
    for (int i = tid; i < 2048; i += NTHR) p[i] = make_uint4(0u, 0u, 0u, 0u);
    float* cb = (float*)(smem + CB_OFF);
    for (int i = tid; i < BB * HC; i += NTHR) cb[i] = 0.f;
  }
  // ---- stage x_0, mask_0 ----
  {
    const int ta = dir ? (SS - 1) : 0;
    const int bm = tid >> 4, e0 = (tid & 15) * 16;
    const float* xs = x + ((size_t)bm * SS + ta) * EE + e0;
    float xr0[16];
    #pragma unroll
    for (int i = 0; i < 16; ++i) xr0[i] = xs[i];
    #pragma unroll
    for (int hfi = 0; hfi < 2; ++hfi) {
      bf16x8 vv;
      #pragma unroll
      for (int i = 0; i < 8; ++i) vv[i] = (short)f2bf(xr0[hfi * 8 + i]);
      *(bf16x8*)(smem + XB_OFF + fragAddr(bm, e0 + hfi * 8)) = vv;
    }
    if (tid < BB) ((float*)(smem + MB_OFF))[tid] = mask[(size_t)tid * SS + ta];
  }
  __syncthreads();

  for (int t = 0; t < SS; ++t) {
    const int par = t & 1;
    uint32_t* HbufP = hbufB + (dir * 2 + par) * (NG * 256);
    uint32_t* SbufP = sbufB + (dir * 2 + par) * (NG * 256);
    const float* mb = (const float*)(smem + MB_OFF + par * 128);

    // ---- phase 1: z GEMMs (+ Us GEMM on waves 0,1) ----
    f32x4 accZ; accZ[0] = breg; accZ[1] = breg; accZ[2] = breg; accZ[3] = breg;
    f32x4 accU = {0.f, 0.f, 0.f, 0.f};
    #pragma unroll
    for (int kk = 0; kk < 8; ++kk) {
      const int fb = ((mt * 8 + kk) << 10) + lane * 16;
      bf16x8 ah = *(const bf16x8*)(smem + HF_OFF + fb);
      bf16x8 as = *(const bf16x8*)(smem + SF_OFF + fb);
      bf16x8 ax = *(const bf16x8*)(smem + XB_OFF + fb);
      accZ = mfma16(ax, WxF[kk], accZ);
      accZ = mfma16(ah, WhF[kk], accZ);
      accZ = mfma16(as, WsF[kk], accZ);
      if (w < 2) accU = mfma16(as, UF[kk], accU);
    }

    // ---- phase 1b: prefetch x_{t+1}, mask_{t+1} into regs ----
    float xr[16]; float mreg = 0.f;
    if (t + 1 < SS) {
      const int ta = dir ? (SS - 2 - t) : (t + 1);
      const int bm = tid >> 4, e0 = (tid & 15) * 16;
      const float* xs = x + ((size_t)bm * SS + ta) * EE + e0;
      #pragma unroll
      for (int i = 0; i < 16; ++i) xr[i] = xs[i];
      if (tid < BB) mreg = mask[(size_t)tid * SS + ta];
    }

    // ---- phase 2: spill z tiles (C layout: col=lane&15, row=(lane>>4)*4+i) ----
    {
      float* zb = (float*)(smem + ZB_OFF);
      #pragma unroll
      for (int i = 0; i < 4; ++i)
        zb[(mt * 4 + q) * 256 + (lq * 4 + i) * 16 + lr] = accZ[i];
      if (w < 2) {
        float* ub = (float*)(smem + US_OFF);
        #pragma unroll
        for (int i = 0; i < 4; ++i)
          ub[mt * 256 + (lq * 4 + i) * 16 + lr] = accU[i];
      }
    }
    __syncthreads();

    // ---- phase 3: gates, c/h update, outputs, publish h_new ----
    const int bm = tid >> 4, cc = tid & 15;
    const int mtL = bm >> 4, rr = bm & 15;
    float mval;
    {
      const float* zb = (const float*)(smem + ZB_OFF);
      float zi = zb[(mtL * 4 + 0) * 256 + rr * 16 + cc];
      float zf = zb[(mtL * 4 + 1) * 256 + rr * 16 + cc];
      float zg = zb[(mtL * 4 + 2) * 256 + rr * 16 + cc];
      float zo = zb[(mtL * 4 + 3) * 256 + rr * 16 + cc];
      float* cb = (float*)(smem + CB_OFF);
      float cold = cb[bm * 16 + cc];
      mval = mb[bm];
      float cn = sigm(zf) * cold + sigm(zi) * tanhfast(zg);
      float hnew = sigm(zo) * tanhfast(cn);
      float cbl = mval * cn + (1.f - mval) * cold;
      cb[bm * 16 + cc] = cbl;
      float hold = bf2f(*(const uint16_t*)(smem + HF_OFF + fragAddr(bm, g * HC + cc)));
      float hbl = mval * hnew + (1.f - mval) * hold;
      const int tact = dir ? (SS - 1 - t) : t;
      size_t ob = ((size_t)tact * BB + bm) * (2 * HH) + (size_t)dir * HH + g * HC + cc;
      out[ob] = hbl;                 // h_out
      out[ob + 8388608] = cbl;       // c_out
      uint32_t hb = f2bf(hnew);
      uint32_t pv = (uint32_t)__shfl_xor((int)hb, 1);
      if ((tid & 1) == 0) {
        uint32_t word = (hb & 0xffffu) | (pv << 16);
        __hip_atomic_store(&HbufP[g * 256 + (tid >> 1)], word,
                           __ATOMIC_RELAXED, __HIP_MEMORY_SCOPE_AGENT);
      }
    }
    __syncthreads();
    if (tid == 0)
      __hip_atomic_store(&flagH[g * 16], (uint32_t)(t + 1),
                         __ATOMIC_RELAXED, __HIP_MEMORY_SCOPE_AGENT);

    // ---- phase 6: consume h slices -> HF holds pre-blend h_new; stash old in regs ----
    uint32_t oldw[2][4];
    #pragma unroll
    for (int ssl = 0; ssl < 2; ++ssl) {
      const int sl = w + ssl * 8;
      if (lane == 0) {
        while (__hip_atomic_load(&flagH[sl * 16], __ATOMIC_RELAXED,
                                 __HIP_MEMORY_SCOPE_AGENT) < (uint32_t)(t + 1)) {}
      }
      const uint32_t* src = HbufP + sl * 256;
      #pragma unroll
      for (int ww = 0; ww < 4; ++ww) {
        const int word = ww * 64 + lane;
        uint32_t v = __hip_atomic_load(&src[word], __ATOMIC_RELAXED, __HIP_MEMORY_SCOPE_AGENT);
        const int mrow = word >> 3, c0 = (word & 7) * 2;
        const int fa = fragAddr(mrow, sl * HC + c0);
        oldw[ssl][ww] = *(uint32_t*)(smem + HF_OFF + fa);
        *(uint32_t*)(smem + HF_OFF + fa) = v;
      }
    }
    __syncthreads();

    // ---- phase 7: Uh GEMM on pre-blend h_new (waves 2,3) ----
    if (w == 2 || w == 3) {
      f32x4 aU = {0.f, 0.f, 0.f, 0.f};
      #pragma unroll
      for (int kk = 0; kk < 8; ++kk) {
        bf16x8 ah = *(const bf16x8*)(smem + HF_OFF + (((w & 1) * 8 + kk) << 10) + lane * 16);
        aU = mfma16(ah, UF[kk], aU);
      }
      float* ub = (float*)(smem + UH_OFF);
      #pragma unroll
      for (int i = 0; i < 4; ++i)
        ub[(w & 1) * 256 + (lq * 4 + i) * 16 + lr] = aU[i];
    }
    __syncthreads();

    // ---- phase 8: re-blend HF to h_{t+1}; s_new; outputs; publish s ----
    #pragma unroll
    for (int ssl = 0; ssl < 2; ++ssl) {
      const int sl = w + ssl * 8;
      #pragma unroll
      for (int ww = 0; ww < 4; ++ww) {
        const int word = ww * 64 + lane;
        const int mrow = word >> 3, c0 = (word & 7) * 2;
        const int fa = fragAddr(mrow, sl * HC + c0);
        uint32_t nv = *(uint32_t*)(smem + HF_OFF + fa);
        uint32_t ov = oldw[ssl][ww];
        float mv = mb[mrow];
        float b0 = mv * bf2f(nv & 0xffffu) + (1.f - mv) * bf2f(ov & 0xffffu);
        float b1 = mv * bf2f(nv >> 16)     + (1.f - mv) * bf2f(ov >> 16);
        *(uint32_t*)(smem + HF_OFF + fa) = (f2bf(b0) & 0xffffu) | (f2bf(b1) << 16);
      }
    }
    {
      const float* ub1 = (const float*)(smem + US_OFF);
      const float* ub2 = (const float*)(smem + UH_OFF);
      float sv = ub1[mtL * 256 + rr * 16 + cc] + ub2[mtL * 256 + rr * 16 + cc] + bsreg;
      float snew = tanhfast(sv);
      float sold = bf2f(*(const uint16_t*)(smem + SF_OFF + fragAddr(bm, g * HC + cc)));
      float sbl = mval * snew + (1.f - mval) * sold;
      const int tact = dir ? (SS - 1 - t) : t;
      out[((size_t)tact * BB + bm) * (2 * HH) + (size_t)dir * HH + g * HC + cc + 16777216] = sbl;
      uint32_t sb = f2bf(snew);
      uint32_t pv = (uint32_t)__shfl_xor((int)sb, 1);
      if ((tid & 1) == 0) {
        uint32_t word = (sb & 0xffffu) | (pv << 16);
        __hip_atomic_store(&SbufP[g * 256 + (tid >> 1)], word,
                           __ATOMIC_RELAXED, __HIP_MEMORY_SCOPE_AGENT);
      }
    }
    __syncthreads();
    if (tid == 0)
      __hip_atomic_store(&flagS[g * 16], (uint32_t)(t + 1),
                         __ATOMIC_RELAXED, __HIP_MEMORY_SCOPE_AGENT);

    // ---- phase 9: consume s slices (blend into SF) ----
    #pragma unroll
    for (int ssl = 0; ssl < 2; ++ssl) {
      const int sl = w + ssl * 8;
      if (lane == 0) {
        while (__hip_atomic_load(&flagS[sl * 16], __ATOMIC_RELAXED,
                                 __HIP_MEMORY_SCOPE_AGENT) < (uint32_t)(t + 1)) {}
      }
      const uint32_t* src = SbufP + sl * 256;
      #pragma unroll
      for (int ww = 0; ww < 4; ++ww) {
        const int word = ww * 64 + lane;
        uint32_t v = __hip_atomic_load(&src[word], __ATOMIC_RELAXED, __HIP_MEMORY_SCOPE_AGENT);
        const int mrow = word >> 3, c0 = (word & 7) * 2;
        const int fa = fragAddr(mrow, sl * HC + c0);
        uint32_t ov = *(uint32_t*)(smem + SF_OFF + fa);
        float mv = mb[mrow];
        float b0 = mv * bf2f(v & 0xffffu) + (1.f - mv) * bf2f(ov & 0xffffu);
        float b1 = mv * bf2f(v >> 16)     + (1.f - mv) * bf2f(ov >> 16);
        *(uint32_t*)(smem + SF_OFF + fa) = (f2bf(b0) & 0xffffu) | (f2bf(b1) << 16);
      }
    }
    // ---- phase 9b: write prefetched x_{t+1}, mask_{t+1} ----
    if (t + 1 < SS) {
      const int bm2 = tid >> 4, e0 = (tid & 15) * 16;
      #pragma unroll
      for (int hfi = 0; hfi < 2; ++hfi) {
        bf16x8 vv;
        #pragma unroll
        for (int i = 0; i < 8; ++i) vv[i] = (short)f2bf(xr[hfi * 8 + i]);
        *(bf16x8*)(smem + XB_OFF + fragAddr(bm2, e0 + hfi * 8)) = vv;
      }
      float* mbn = (float*)(smem + MB_OFF + ((t + 1) & 1) * 128);
      if (tid < BB) mbn[tid] = mreg;
    }
    __syncthreads();
  }
}

extern "C" void kernel_launch(void* const* d_in, const int* in_sizes, int n_in,
                              void* d_out, int out_size, void* d_ws, size_t ws_size,
                              hipStream_t stream) {
  (void)in_sizes; (void)n_in; (void)out_size; (void)ws_size;
  const float* x    = (const float*)d_in[0];
  const float* mask = (const float*)d_in[1];
  // d_in[2] = idx (unused by reference)
  const float* Wx_f = (const float*)d_in[3];
  const float* Wh_f = (const float*)d_in[4];
  const float* Ws_f = (const float*)d_in[5];
  const float* b_f  = (const float*)d_in[6];
  const float* Us_f = (const float*)d_in[7];
  const float* Uh_f = (const float*)d_in[8];
  const float* bs_f = (const float*)d_in[9];
  const float* Wx_r = (const float*)d_in[10];
  const float* Wh_r = (const float*)d_in[11];
  const float* Ws_r = (const float*)d_in[12];
  const float* b_r  = (const float*)d_in[13];
  const float* Us_r = (const float*)d_in[14];
  const float* Uh_r = (const float*)d_in[15];
  const float* bs_r = (const float*)d_in[16];
  float* out = (float*)d_out;
  uint32_t* ws = (uint32_t*)d_ws;

  init_flags<<<dim3(4), dim3(256), 0, stream>>>(ws);
  slstm_persistent<<<dim3(NWG), dim3(NTHR), 0, stream>>>(
      x, mask, Wx_f, Wh_f, Ws_f, b_f, Us_f, Uh_f, bs_f,
      Wx_r, Wh_r, Ws_r, b_r, Us_r, Uh_r, bs_r, out, ws);
}